// Round 1
// baseline (229.249 us; speedup 1.0000x reference)
//
#include <hip/hip_runtime.h>

// ---------------------------------------------------------------------------
// Workspace:
//   idxb 0        : (2048,100) int       819200
//   sdn  819200   : (6,3,128)              9216
//   stp  828416   : 6 layers x 32 banks x 256 f32  196608   (BN partials)
//   fo   1025024  : 3 x (2048,256)       6291456
//   p0.. 7316480  : 6 x (2048,128)       6291456
// BN stats: agg blocks atomically add (val, val^2) into bank (row&31);
// consumers (gemm/down) reduce the 32 banks. Eliminates 3 stats launches.
// ---------------------------------------------------------------------------

// ---------------------------------------------------------------------------
// GEMM body (reg-prefetched LDS W): out[r0..r0+7, :256] = bn_relu?(in) @ W + b.
// 8 rows/block, 256 threads = 2 rows x 4 cols. stp: 32-bank partials.
// W chunk c+1 is prefetched into registers while chunk c computes, so the
// global W latency hides under the FMA block even at 1 wave/SIMD.
// ---------------------------------------------------------------------------
__device__ __forceinline__ void do_gemm(
    const float* __restrict__ in, const float* __restrict__ stp,
    const float* __restrict__ gm, const float* __restrict__ bt,
    const float* __restrict__ W, const float* __restrict__ bi,
    float* __restrict__ out, int rb, char* smemc)
{
    float* rows  = (float*)smemc;           // 1024 floats
    float* wch   = rows + 1024;             // 4096 floats (16 KB)
    float* scale = wch + 4096;              // 128
    float* shift = scale + 128;             // 128
    int t = threadIdx.x;
    const float4* W4 = (const float4*)W;
    float4* wch4 = (float4*)wch;

    // issue chunk-0 W loads first so they fly during the stats reduce
    float4 rw[4];
    #pragma unroll
    for (int i = 0; i < 4; ++i) rw[i] = W4[t + 256*i];

    if (t < 128) {
        float sc = 1.0f, sf = 0.0f;
        if (stp) {
            float sm = 0.0f, sq = 0.0f;
            #pragma unroll 8
            for (int bk = 0; bk < 32; ++bk) {
                sm += stp[bk*256 + t];
                sq += stp[bk*256 + 128 + t];
            }
            float mu  = sm * (1.0f/2048.0f);
            float var = sq * (1.0f/2048.0f) - mu*mu;
            sc = rsqrtf(var + 1e-5f) * gm[t];
            sf = bt[t] - mu*sc;
        }
        scale[t] = sc; shift[t] = sf;
    }
    __syncthreads();
    int r0 = rb * 8;
    {
        float4 v = ((const float4*)(in + r0*128))[t];
        if (stp) {
            int c4 = (t & 31) << 2;
            v.x = fmaxf(v.x*scale[c4  ] + shift[c4  ], 0.0f);
            v.y = fmaxf(v.y*scale[c4+1] + shift[c4+1], 0.0f);
            v.z = fmaxf(v.z*scale[c4+2] + shift[c4+2], 0.0f);
            v.w = fmaxf(v.w*scale[c4+3] + shift[c4+3], 0.0f);
        }
        ((float4*)rows)[t] = v;
    }
    // chunk 0 -> LDS (compiler inserts vmcnt wait for rw)
    #pragma unroll
    for (int i = 0; i < 4; ++i) wch4[t + 256*i] = rw[i];
    __syncthreads();

    int cb = t & 63, rp = (t >> 6) << 1;
    const float* a0r = rows + rp*128;
    const float* a1r = a0r + 128;
    float4 acc0 = make_float4(0.f,0.f,0.f,0.f);
    float4 acc1 = make_float4(0.f,0.f,0.f,0.f);
    for (int c = 0; c < 8; ++c) {
        if (c < 7) {
            #pragma unroll
            for (int i = 0; i < 4; ++i) rw[i] = W4[(c+1)*1024 + t + 256*i];
        }
        int kb = c*16;
        #pragma unroll
        for (int k = 0; k < 16; k += 4) {
            float4 a0 = *(const float4*)(a0r + kb + k);
            float4 a1 = *(const float4*)(a1r + kb + k);
            float4 w;
            w = wch4[(k+0)*64+cb];
            acc0.x += a0.x*w.x; acc0.y += a0.x*w.y; acc0.z += a0.x*w.z; acc0.w += a0.x*w.w;
            acc1.x += a1.x*w.x; acc1.y += a1.x*w.y; acc1.z += a1.x*w.z; acc1.w += a1.x*w.w;
            w = wch4[(k+1)*64+cb];
            acc0.x += a0.y*w.x; acc0.y += a0.y*w.y; acc0.z += a0.y*w.z; acc0.w += a0.y*w.w;
            acc1.x += a1.y*w.x; acc1.y += a1.y*w.y; acc1.z += a1.y*w.z; acc1.w += a1.y*w.w;
            w = wch4[(k+2)*64+cb];
            acc0.x += a0.z*w.x; acc0.y += a0.z*w.y; acc0.z += a0.z*w.z; acc0.w += a0.z*w.w;
            acc1.x += a1.z*w.x; acc1.y += a1.z*w.y; acc1.z += a1.z*w.z; acc1.w += a1.z*w.w;
            w = wch4[(k+3)*64+cb];
            acc0.x += a0.w*w.x; acc0.y += a0.w*w.y; acc0.z += a0.w*w.z; acc0.w += a0.w*w.w;
            acc1.x += a1.w*w.x; acc1.y += a1.w*w.y; acc1.z += a1.w*w.z; acc1.w += a1.w*w.w;
        }
        if (c < 7) {
            __syncthreads();                 // everyone done reading chunk c
            #pragma unroll
            for (int i = 0; i < 4; ++i) wch4[t + 256*i] = rw[i];
            __syncthreads();                 // chunk c+1 visible
        }
    }
    float4 b4 = ((const float4*)bi)[cb];
    acc0.x += b4.x; acc0.y += b4.y; acc0.z += b4.z; acc0.w += b4.w;
    acc1.x += b4.x; acc1.y += b4.y; acc1.z += b4.z; acc1.w += b4.w;
    ((float4*)out)[(r0+rp  )*64 + cb] = acc0;
    ((float4*)out)[(r0+rp+1)*64 + cb] = acc1;
}

// ---------------------------------------------------------------------------
// K1: wave-sync knn (0..511) + gemmA (512..1279) + zero stp (1280..1471) +
// dirs norm (1472). knn algorithm verified r8-r12.
// ---------------------------------------------------------------------------
__global__ void k1_kernel(const float* __restrict__ verts, const float* __restrict__ dirs,
                          const float* __restrict__ x,
                          const float* __restrict__ convW, const float* __restrict__ convB,
                          int* __restrict__ idxout, float* __restrict__ sdn,
                          float* __restrict__ stp, float* __restrict__ fo)
{
    __shared__ __align__(16) char smem[21504];
    int t = threadIdx.x;
    int blk = blockIdx.x;

    if (blk >= 1280) {
        if (blk == 1472) {
            for (int i = t; i < 768; i += 256) {
                int l = i >> 7, k = i & 127;
                float a = dirs[l*384 + k];
                float b = dirs[l*384 + 128 + k];
                float c = dirs[l*384 + 256 + k];
                float nrm = sqrtf(a*a + b*b + c*c);
                float inv = 1.0f / fmaxf(nrm, 1e-12f);
                sdn[l*384 + k]       = a*inv;
                sdn[l*384 + 128 + k] = b*inv;
                sdn[l*384 + 256 + k] = c*inv;
            }
        } else {
            stp[(blk - 1280)*256 + t] = 0.0f;     // 192 blocks x 256 = 49152
        }
        return;
    }
    if (blk >= 512) {
        int g = blk - 512;
        int s = g >> 8, rb = g & 255;
        int wi = (s==0) ? 0 : (s==1) ? 1 : 3;
        do_gemm(x, (const float*)0, (const float*)0, (const float*)0,
                convW + wi*32768, convB + wi*256, fo + s*524288, rb, smem);
        return;
    }

    // ---------------- knn: one wave per vertex ----------------
    float* xs  = (float*)smem;
    float* ys  = xs + 1024;
    float* zs  = ys + 1024;
    float* sqs = zs + 1024;
    unsigned int* histBase = (unsigned int*)(smem + 16384);
    unsigned int* selBase  = (unsigned int*)(smem + 20480);

    int w = t >> 6, l = t & 63;
    int vglob = blk*4 + w;
    int b = vglob >> 10;
    int v = vglob & 1023;
    unsigned long long* keys = (unsigned long long*)smem + w*256;  // alias xs/ys
    unsigned int* hist = histBase + w*256;
    unsigned int* sel  = selBase + w*4;

    const float* vb = verts + b * 3072;
    for (int i = t; i < 1024; i += 256) {
        float xx = vb[i*3+0], yy = vb[i*3+1], zz = vb[i*3+2];
        xs[i] = xx; ys[i] = yy; zs[i] = zz;
        sqs[i] = xx*xx + yy*yy + zz*zz;
    }
    __syncthreads();

    float cx = xs[v], cy = ys[v], cz = zs[v], csq = sqs[v];
    unsigned long long K16[16];
    #pragma unroll
    for (int q = 0; q < 16; ++q) {
        int j = q*64 + l;
        float dot = cx*xs[j] + cy*ys[j] + cz*zs[j];
        float d = -2.0f*dot + csq + sqs[j];
        unsigned int u = __float_as_uint(d);
        u = (u & 0x80000000u) ? ~u : (u | 0x80000000u);
        K16[q] = (((unsigned long long)u) << 32) | (unsigned long long)j;
    }
    #pragma unroll
    for (int i = 0; i < 4; ++i) hist[l*4 + i] = 0u;
    __syncthreads();

    #pragma unroll
    for (int q = 0; q < 16; ++q)
        atomicAdd(&hist[(unsigned int)(K16[q] >> 56)], 1u);
    __syncthreads();

    {
        unsigned int h0 = hist[l*4], h1 = hist[l*4+1], h2 = hist[l*4+2], h3 = hist[l*4+3];
        unsigned int c1 = h0, c2 = h0+h1, c3 = h0+h1+h2, T = c3+h3;
        unsigned int xacc = T;
        #pragma unroll
        for (int off = 1; off < 64; off <<= 1) {
            unsigned int y = __shfl_up(xacc, off, 64);
            if (l >= off) xacc += y;
        }
        unsigned int P = xacc - T;
        unsigned int ex[4] = {P, P+c1, P+c2, P+c3};
        unsigned int hh[4] = {h0, h1, h2, h3};
        #pragma unroll
        for (int i = 0; i < 4; ++i) {
            if (ex[i] < 101u && ex[i] + hh[i] >= 101u) {
                sel[0] = (unsigned int)(l*4 + i);
                sel[1] = 101u - ex[i];
            }
        }
    }
    __syncthreads();
    unsigned int P8 = sel[0], rank2 = sel[1];
    #pragma unroll
    for (int i = 0; i < 4; ++i) hist[l*4 + i] = 0u;
    __syncthreads();

    #pragma unroll
    for (int q = 0; q < 16; ++q)
        if ((unsigned int)(K16[q] >> 56) == P8)
            atomicAdd(&hist[(unsigned int)(K16[q] >> 48) & 0xFFu], 1u);
    __syncthreads();

    {
        unsigned int h0 = hist[l*4], h1 = hist[l*4+1], h2 = hist[l*4+2], h3 = hist[l*4+3];
        unsigned int c1 = h0, c2 = h0+h1, c3 = h0+h1+h2, T = c3+h3;
        unsigned int xacc = T;
        #pragma unroll
        for (int off = 1; off < 64; off <<= 1) {
            unsigned int y = __shfl_up(xacc, off, 64);
            if (l >= off) xacc += y;
        }
        unsigned int P = xacc - T;
        unsigned int ex[4] = {P, P+c1, P+c2, P+c3};
        unsigned int hh[4] = {h0, h1, h2, h3};
        #pragma unroll
        for (int i = 0; i < 4; ++i) {
            if (ex[i] < rank2 && ex[i] + hh[i] >= rank2) {
                sel[2] = (P8 << 8) | (unsigned int)(l*4 + i);
                sel[3] = 0u;
            }
        }
    }
    __syncthreads();
    unsigned int P16 = sel[2];

    #pragma unroll
    for (int q = 0; q < 16; ++q) {
        if ((unsigned int)(K16[q] >> 48) <= P16) {
            unsigned int pos = atomicAdd(&sel[3], 1u);
            if (pos < 256u) keys[pos] = K16[q];
        }
    }
    __syncthreads();
    unsigned int cnt = sel[3];

    unsigned long long K[4];
    #pragma unroll
    for (int q = 0; q < 4; ++q) {
        unsigned int e = (unsigned int)(l*4 + q);
        K[q] = (e < cnt) ? keys[e] : 0xFFFFFFFFFFFFFFFFULL;
    }

    auto cswap = [&](int qa, int qb, int k) {
        int e = (l << 2) + qa;
        bool up = ((e & k) == 0);
        unsigned long long a = K[qa], bb2 = K[qb];
        unsigned long long mn = a < bb2 ? a : bb2;
        unsigned long long mx = a < bb2 ? bb2 : a;
        K[qa] = up ? mn : mx;
        K[qb] = up ? mx : mn;
    };
    #pragma unroll
    for (int k = 2; k <= 256; k <<= 1) {
        for (int j = k >> 1; j >= 4; j >>= 1) {
            int lj = j >> 2;
            #pragma unroll
            for (int q = 0; q < 4; ++q) {
                unsigned long long other = __shfl_xor(K[q], lj, 64);
                int e = (l << 2) + q;
                bool up = ((e & k) == 0);
                bool lower = ((l & lj) == 0);
                bool takeMin = (lower == up);
                unsigned long long mn = K[q] < other ? K[q] : other;
                unsigned long long mx = K[q] < other ? other : K[q];
                K[q] = takeMin ? mn : mx;
            }
        }
        if (k >= 4) { cswap(0, 2, k); cswap(1, 3, k); }
        cswap(0, 1, k); cswap(2, 3, k);
    }

    #pragma unroll
    for (int q = 0; q < 4; ++q) {
        int e = l*4 + q;
        if (e >= 1 && e <= 100)
            idxout[vglob*100 + (e-1)] = (int)(K[q] & 0xFFFFFFFFu);
    }
}

// ---------------------------------------------------------------------------
// Agg + fused BN-partials: 256 threads = 2 rows/block. After writing the
// row, each thread adds (val, val^2) into stp bank (row & 31) (64 adds per
// address across the launch; fire-and-forget atomics).
// ---------------------------------------------------------------------------
__global__ void agg_kernel(const int* __restrict__ idx, const float* __restrict__ verts,
                           const float* __restrict__ sdn, const float* __restrict__ fo,
                           int n0, int n1, int n2, int d0, int d1, int d2,
                           float* o0, float* o1, float* o2,
                           float* s0p, float* s1p, float* s2p)
{
    __shared__ float4 ds4s[200];
    __shared__ int jss[200];
    int slot = blockIdx.y;
    int n  = slot==0 ? n0 : slot==1 ? n1 : n2;
    int dI = slot==0 ? d0 : slot==1 ? d1 : d2;
    float* outp = slot==0 ? o0 : slot==1 ? o1 : o2;
    float* stp  = slot==0 ? s0p : slot==1 ? s1p : s2p;
    const float* fos = fo + slot * 524288;
    const float* sd = sdn + dI * 384;

    int t = threadIdx.x;
    int h = t >> 7, tt = t & 127;
    float4* ds4 = ds4s + h*100;
    int* js = jss + h*100;
    int r = blockIdx.x*2 + h;
    int b = r >> 10;

    if (tt < n) {
        int j = idx[r*100 + tt];
        js[tt] = j;
        const float* pj = verts + (b*1024 + j)*3;
        const float* pv = verts + r*3;
        float dx = pj[0]-pv[0], dy = pj[1]-pv[1], dz = pj[2]-pv[2];
        float nm = sqrtf(dx*dx + dy*dy + dz*dz);
        float inv = 1.0f / fmaxf(nm, 1e-12f);
        ds4[tt] = make_float4(dx*inv, dy*inv, dz*inv, 0.0f);
    }
    __syncthreads();
    float s0 = sd[tt], s1 = sd[128+tt], s2 = sd[256+tt];
    int bb = b * 1024;
    float m = -3.0e38f;
    for (int q = 0; q < n; q += 5) {
        float th[5];
        const float* p[5];
        #pragma unroll
        for (int u = 0; u < 5; ++u) {
            float4 dq = ds4[q+u];
            th[u] = fmaxf(dq.x*s0 + dq.y*s1 + dq.z*s2, 0.0f);
            p[u] = fos + (size_t)(bb + js[q+u])*256 + 128 + tt;
        }
        float vv[5];
        #pragma unroll
        for (int u = 0; u < 5; ++u) vv[u] = *p[u];
        #pragma unroll
        for (int u = 0; u < 5; ++u) m = fmaxf(m, th[u]*vv[u]);
    }
    float val = fos[r*256 + tt] + m;
    outp[r*128 + tt] = val;
    float* bank = stp + (r & 31)*256;
    atomicAdd(&bank[tt], val);
    atomicAdd(&bank[128+tt], val*val);
}

// ---------------------------------------------------------------------------
// Standalone gemm, up to 2 slots via blockIdx.y. grid (256, nslots), 256 thr.
// ---------------------------------------------------------------------------
__global__ void gemm2_kernel(
    const float* inA, const float* stA, const float* gA, const float* beA,
    const float* WA, const float* biA, float* foA,
    const float* inB, const float* stB, const float* gB, const float* beB,
    const float* WB, const float* biB, float* foB)
{
    __shared__ __align__(16) char smem[21504];
    if (blockIdx.y == 0)
        do_gemm(inA, stA, gA, beA, WA, biA, foA, blockIdx.x, smem);
    else
        do_gemm(inB, stB, gB, beB, WB, biB, foB, blockIdx.x, smem);
}

// ---------------------------------------------------------------------------
// Down-proj (reg-prefetched LDS W): [bn(p0)|bn(p1)|bn(p2)] (384) @ dW + db,
// relu. 8 rows/block (256 blocks). BN scales from 32-bank partials.
// ---------------------------------------------------------------------------
__global__ void down_kernel(
    const float* __restrict__ p0, const float* __restrict__ s0p,
    const float* __restrict__ g0, const float* __restrict__ be0,
    const float* __restrict__ p1, const float* __restrict__ s1p,
    const float* __restrict__ g1, const float* __restrict__ be1,
    const float* __restrict__ p2, const float* __restrict__ s2p,
    const float* __restrict__ g2, const float* __restrict__ be2,
    const float* __restrict__ dW, const float* __restrict__ db,
    float* __restrict__ out)
{
    __shared__ float rows[8*384];
    __shared__ float wch[16*256];
    __shared__ float scale[384], shift[384];
    int t = threadIdx.x;
    int r0 = blockIdx.x * 8;
    const float4* W4 = (const float4*)dW;
    float4* wch4 = (float4*)wch;

    // issue chunk-0 W loads first so they fly during the stats reduce
    float4 rw[4];
    #pragma unroll
    for (int i = 0; i < 4; ++i) rw[i] = W4[t + 256*i];

    for (int c = t; c < 384; c += 256) {
        int seg = c >> 7, cc = c & 127;
        const float* stp = seg==0 ? s0p : seg==1 ? s1p : s2p;
        const float* g   = seg==0 ? g0  : seg==1 ? g1  : g2;
        const float* be  = seg==0 ? be0 : seg==1 ? be1 : be2;
        float sm = 0.0f, sq = 0.0f;
        #pragma unroll 8
        for (int bk = 0; bk < 32; ++bk) {
            sm += stp[bk*256 + cc];
            sq += stp[bk*256 + 128 + cc];
        }
        float mu  = sm * (1.0f/2048.0f);
        float var = sq * (1.0f/2048.0f) - mu*mu;
        float s = rsqrtf(var + 1e-5f) * g[cc];
        scale[c] = s;
        shift[c] = be[cc] - mu*s;
    }
    __syncthreads();
    for (int q = t; q < 768; q += 256) {
        int row = q / 96, rem = q - row*96;
        int c4 = rem << 2;
        int seg = c4 >> 7, cc = c4 & 127;
        const float* ps = seg==0 ? p0 : seg==1 ? p1 : p2;
        float4 v = *(const float4*)(ps + (r0+row)*128 + cc);
        v.x = fmaxf(v.x*scale[c4  ] + shift[c4  ], 0.0f);
        v.y = fmaxf(v.y*scale[c4+1] + shift[c4+1], 0.0f);
        v.z = fmaxf(v.z*scale[c4+2] + shift[c4+2], 0.0f);
        v.w = fmaxf(v.w*scale[c4+3] + shift[c4+3], 0.0f);
        *(float4*)&rows[row*384 + c4] = v;
    }
    // chunk 0 -> LDS (compiler inserts vmcnt wait for rw)
    #pragma unroll
    for (int i = 0; i < 4; ++i) wch4[t + 256*i] = rw[i];
    __syncthreads();

    int cb = t & 63, rp = (t >> 6) << 1;
    const float* a0r = rows + rp*384;
    const float* a1r = a0r + 384;
    float4 acc0 = make_float4(0.f,0.f,0.f,0.f);
    float4 acc1 = make_float4(0.f,0.f,0.f,0.f);
    for (int c = 0; c < 24; ++c) {
        if (c < 23) {
            #pragma unroll
            for (int i = 0; i < 4; ++i) rw[i] = W4[(c+1)*1024 + t + 256*i];
        }
        int kb = c*16;
        #pragma unroll
        for (int k = 0; k < 16; k += 4) {
            float4 a0 = *(const float4*)(a0r + kb + k);
            float4 a1 = *(const float4*)(a1r + kb + k);
            float4 w;
            w = wch4[(k+0)*64+cb];
            acc0.x += a0.x*w.x; acc0.y += a0.x*w.y; acc0.z += a0.x*w.z; acc0.w += a0.x*w.w;
            acc1.x += a1.x*w.x; acc1.y += a1.x*w.y; acc1.z += a1.x*w.z; acc1.w += a1.x*w.w;
            w = wch4[(k+1)*64+cb];
            acc0.x += a0.y*w.x; acc0.y += a0.y*w.y; acc0.z += a0.y*w.z; acc0.w += a0.y*w.w;
            acc1.x += a1.y*w.x; acc1.y += a1.y*w.y; acc1.z += a1.y*w.z; acc1.w += a1.y*w.w;
            w = wch4[(k+2)*64+cb];
            acc0.x += a0.z*w.x; acc0.y += a0.z*w.y; acc0.z += a0.z*w.z; acc0.w += a0.z*w.w;
            acc1.x += a1.z*w.x; acc1.y += a1.z*w.y; acc1.z += a1.z*w.z; acc1.w += a1.z*w.w;
            w = wch4[(k+3)*64+cb];
            acc0.x += a0.w*w.x; acc0.y += a0.w*w.y; acc0.z += a0.w*w.z; acc0.w += a0.w*w.w;
            acc1.x += a1.w*w.x; acc1.y += a1.w*w.y; acc1.z += a1.w*w.z; acc1.w += a1.w*w.w;
        }
        if (c < 23) {
            __syncthreads();                 // everyone done reading chunk c
            #pragma unroll
            for (int i = 0; i < 4; ++i) wch4[t + 256*i] = rw[i];
            __syncthreads();                 // chunk c+1 visible
        }
    }
    float4 b4 = ((const float4*)db)[cb];
    float4 o0, o1;
    o0.x = fmaxf(acc0.x + b4.x, 0.0f); o0.y = fmaxf(acc0.y + b4.y, 0.0f);
    o0.z = fmaxf(acc0.z + b4.z, 0.0f); o0.w = fmaxf(acc0.w + b4.w, 0.0f);
    o1.x = fmaxf(acc1.x + b4.x, 0.0f); o1.y = fmaxf(acc1.y + b4.y, 0.0f);
    o1.z = fmaxf(acc1.z + b4.z, 0.0f); o1.w = fmaxf(acc1.w + b4.w, 0.0f);
    ((float4*)out)[(r0+rp  )*64 + cb] = o0;
    ((float4*)out)[(r0+rp+1)*64 + cb] = o1;
}

// ---------------------------------------------------------------------------
extern "C" void kernel_launch(void* const* d_in, const int* in_sizes, int n_in,
                              void* d_out, int out_size, void* d_ws, size_t ws_size,
                              hipStream_t stream)
{
    (void)in_sizes; (void)n_in; (void)out_size; (void)ws_size;
    const float* verts = (const float*)d_in[0];
    const float* x     = (const float*)d_in[1];
    const float* convW = (const float*)d_in[2];
    const float* convB = (const float*)d_in[3];
    const float* dirs  = (const float*)d_in[4];
    const float* gam   = (const float*)d_in[5];
    const float* bet   = (const float*)d_in[6];
    const float* dW    = (const float*)d_in[7];
    const float* db    = (const float*)d_in[8];
    float* out = (float*)d_out;

    char* ws = (char*)d_ws;
    int*   idxb = (int*)(ws);
    float* sdn  = (float*)(ws + 819200);
    float* stp  = (float*)(ws + 828416);         // 6 x 32 x 256 f32
    float* fo   = (float*)(ws + 1025024);        // 3 x (2048,256)
    float* p0   = (float*)(ws + 7316480);
    float* p1   = (float*)(ws + 8365056);
    float* p2   = (float*)(ws + 9413632);
    float* p3   = (float*)(ws + 10462208);
    float* p4   = (float*)(ws + 11510784);
    float* p5   = (float*)(ws + 12559360);       // end ~13.0 MiB

    const float* nf = (const float*)0;
    float* nw = (float*)0;
    float* stL0 = stp,         *stL1 = stp + 8192, *stL2 = stp + 16384;
    float* stL3 = stp + 24576, *stL4 = stp + 32768, *stL5 = stp + 40960;

    // K1: knn + gemmA (L0,L1,L3 from x) + zero stp + dirs norm
    k1_kernel<<<1473, 256, 0, stream>>>(verts, dirs, x, convW, convB,
                                        idxb, sdn, stp, fo);
    // K2: aggA -> p0 (n5,d0,stL0), p1 (n20,d1,stL1), p3 (n100,d3,stL3)
    agg_kernel<<<dim3(1024,3), 256, 0, stream>>>(
        idxb, verts, sdn, fo, 5, 20, 100, 0, 1, 3,
        p0, p1, p3, stL0, stL1, stL3);
    // K3: gemmB: L2 from bn(p1,stL1,g1,b1); L4 from bn(p3,stL3,g3,b3)
    gemm2_kernel<<<dim3(256,2), 256, 0, stream>>>(
        p1, stL1, gam + 128, bet + 128, convW + 65536,  convB + 512,  fo,
        p3, stL3, gam + 384, bet + 384, convW + 131072, convB + 1024, fo + 524288);
    // K4: aggB -> p2 (n20,d2,stL2), p4 (n100,d4,stL4)
    agg_kernel<<<dim3(1024,2), 256, 0, stream>>>(
        idxb, verts, sdn, fo, 20, 100, 0, 2, 4, 0,
        p2, p4, nw, stL2, stL4, nw);
    // K5: gemmC: L5-conv (params3) from bn(p4,stL4,g4,b4)
    gemm2_kernel<<<dim3(256,1), 256, 0, stream>>>(
        p4, stL4, gam + 512, bet + 512, convW + 98304, convB + 768, fo,
        nf, nf, nf, nf, nf, nf, nw);
    // K6: aggC -> p5 (n100,d3,stL5)
    agg_kernel<<<dim3(1024,1), 256, 0, stream>>>(
        idxb, verts, sdn, fo, 100, 0, 0, 3, 0, 0,
        p5, nw, nw, stL5, nw, nw);
    // K7: down: bn(p0,stL0,g0,b0) | bn(p2,stL2,g2,b2) | bn(p5,stL5,g3,b3)
    down_kernel<<<256, 256, 0, stream>>>(
        p0, stL0, gam, bet,
        p2, stL2, gam + 256, bet + 256,
        p5, stL5, gam + 384, bet + 384,
        dW, db, out);
}

// Round 2
// 178.083 us; speedup vs baseline: 1.2873x; 1.2873x over previous
//
#include <hip/hip_runtime.h>

// ---------------------------------------------------------------------------
// Workspace:
//   idxb 0        : (2048,100) int       819200
//   sdn  819200   : (6,3,128)              9216
//   stp  828416   : 6 layers x 32 banks x 256 f32  196608   (BN partials)
//   fo   1025024  : 3 x (2048,256)       6291456
//   p0.. 7316480  : 6 x (2048,128)       6291456
// BN stats: agg blocks atomically add (val, val^2) into bank (row&31);
// consumers (gemm/down) reduce the 32 banks. Eliminates 3 stats launches.
// ---------------------------------------------------------------------------

// ---------------------------------------------------------------------------
// GEMM body (chunked-LDS W): out[r0..r0+7, :256] = bn_relu?(in) @ W + bias.
// 8 rows/block, 256 threads = 2 rows x 4 cols. stp: 32-bank partials.
// Small-chunk (16KB) version: used only inside k1 (LDS capped at 21.5KB so
// knn blocks keep 7 blocks/CU; k1's gemm latency is hidden by co-resident
// knn blocks).  [r1 lesson: reg-prefetch regressed — keep direct loads]
// ---------------------------------------------------------------------------
__device__ __forceinline__ void do_gemm(
    const float* __restrict__ in, const float* __restrict__ stp,
    const float* __restrict__ gm, const float* __restrict__ bt,
    const float* __restrict__ W, const float* __restrict__ bi,
    float* __restrict__ out, int rb, char* smemc)
{
    float* rows  = (float*)smemc;           // 1024 floats
    float* wch   = rows + 1024;             // 4096 floats (16 KB)
    float* scale = wch + 4096;              // 128
    float* shift = scale + 128;             // 128
    int t = threadIdx.x;
    if (t < 128) {
        float sc = 1.0f, sf = 0.0f;
        if (stp) {
            float sm = 0.0f, sq = 0.0f;
            #pragma unroll 8
            for (int bk = 0; bk < 32; ++bk) {
                sm += stp[bk*256 + t];
                sq += stp[bk*256 + 128 + t];
            }
            float mu  = sm * (1.0f/2048.0f);
            float var = sq * (1.0f/2048.0f) - mu*mu;
            sc = rsqrtf(var + 1e-5f) * gm[t];
            sf = bt[t] - mu*sc;
        }
        scale[t] = sc; shift[t] = sf;
    }
    __syncthreads();
    int r0 = rb * 8;
    {
        float4 v = ((const float4*)(in + r0*128))[t];
        if (stp) {
            int c4 = (t & 31) << 2;
            v.x = fmaxf(v.x*scale[c4  ] + shift[c4  ], 0.0f);
            v.y = fmaxf(v.y*scale[c4+1] + shift[c4+1], 0.0f);
            v.z = fmaxf(v.z*scale[c4+2] + shift[c4+2], 0.0f);
            v.w = fmaxf(v.w*scale[c4+3] + shift[c4+3], 0.0f);
        }
        ((float4*)rows)[t] = v;
    }
    int cb = t & 63, rp = (t >> 6) << 1;
    const float* a0r = rows + rp*128;
    const float* a1r = a0r + 128;
    const float4* W4 = (const float4*)W;
    float4* wch4 = (float4*)wch;
    float4 acc0 = make_float4(0.f,0.f,0.f,0.f);
    float4 acc1 = make_float4(0.f,0.f,0.f,0.f);
    for (int c = 0; c < 8; ++c) {
        __syncthreads();
        #pragma unroll
        for (int i = 0; i < 4; ++i)
            wch4[t + 256*i] = W4[c*1024 + t + 256*i];
        __syncthreads();
        int kb = c*16;
        #pragma unroll
        for (int k = 0; k < 16; k += 4) {
            float4 a0 = *(const float4*)(a0r + kb + k);
            float4 a1 = *(const float4*)(a1r + kb + k);
            float4 w;
            w = wch4[(k+0)*64+cb];
            acc0.x += a0.x*w.x; acc0.y += a0.x*w.y; acc0.z += a0.x*w.z; acc0.w += a0.x*w.w;
            acc1.x += a1.x*w.x; acc1.y += a1.x*w.y; acc1.z += a1.x*w.z; acc1.w += a1.x*w.w;
            w = wch4[(k+1)*64+cb];
            acc0.x += a0.y*w.x; acc0.y += a0.y*w.y; acc0.z += a0.y*w.z; acc0.w += a0.y*w.w;
            acc1.x += a1.y*w.x; acc1.y += a1.y*w.y; acc1.z += a1.y*w.z; acc1.w += a1.y*w.w;
            w = wch4[(k+2)*64+cb];
            acc0.x += a0.z*w.x; acc0.y += a0.z*w.y; acc0.z += a0.z*w.z; acc0.w += a0.z*w.w;
            acc1.x += a1.z*w.x; acc1.y += a1.z*w.y; acc1.z += a1.z*w.z; acc1.w += a1.z*w.w;
            w = wch4[(k+3)*64+cb];
            acc0.x += a0.w*w.x; acc0.y += a0.w*w.y; acc0.z += a0.w*w.z; acc0.w += a0.w*w.w;
            acc1.x += a1.w*w.x; acc1.y += a1.w*w.y; acc1.z += a1.w*w.z; acc1.w += a1.w*w.w;
        }
    }
    float4 b4 = ((const float4*)bi)[cb];
    acc0.x += b4.x; acc0.y += b4.y; acc0.z += b4.z; acc0.w += b4.w;
    acc1.x += b4.x; acc1.y += b4.y; acc1.z += b4.z; acc1.w += b4.w;
    ((float4*)out)[(r0+rp  )*64 + cb] = acc0;
    ((float4*)out)[(r0+rp+1)*64 + cb] = acc1;
}

// ---------------------------------------------------------------------------
// Big-chunk GEMM body for standalone gemm2 launches (K3/K5): chunk = k64
// (64KB), 2 chunks instead of 8 -> 4x fewer exposed load-latency boundaries.
// LDS = 69KB; K3's 2 blocks/CU still fit (138KB <= 160KB).
// ---------------------------------------------------------------------------
__device__ __forceinline__ void do_gemm_big(
    const float* __restrict__ in, const float* __restrict__ stp,
    const float* __restrict__ gm, const float* __restrict__ bt,
    const float* __restrict__ W, const float* __restrict__ bi,
    float* __restrict__ out, int rb, char* smemc)
{
    float* rows  = (float*)smemc;           // 1024 floats
    float* wch   = rows + 1024;             // 16384 floats (64 KB)
    float* scale = wch + 16384;             // 128
    float* shift = scale + 128;             // 128
    int t = threadIdx.x;
    if (t < 128) {
        float sc = 1.0f, sf = 0.0f;
        if (stp) {
            float sm = 0.0f, sq = 0.0f;
            #pragma unroll 8
            for (int bk = 0; bk < 32; ++bk) {
                sm += stp[bk*256 + t];
                sq += stp[bk*256 + 128 + t];
            }
            float mu  = sm * (1.0f/2048.0f);
            float var = sq * (1.0f/2048.0f) - mu*mu;
            sc = rsqrtf(var + 1e-5f) * gm[t];
            sf = bt[t] - mu*sc;
        }
        scale[t] = sc; shift[t] = sf;
    }
    __syncthreads();
    int r0 = rb * 8;
    {
        float4 v = ((const float4*)(in + r0*128))[t];
        if (stp) {
            int c4 = (t & 31) << 2;
            v.x = fmaxf(v.x*scale[c4  ] + shift[c4  ], 0.0f);
            v.y = fmaxf(v.y*scale[c4+1] + shift[c4+1], 0.0f);
            v.z = fmaxf(v.z*scale[c4+2] + shift[c4+2], 0.0f);
            v.w = fmaxf(v.w*scale[c4+3] + shift[c4+3], 0.0f);
        }
        ((float4*)rows)[t] = v;
    }
    int cb = t & 63, rp = (t >> 6) << 1;
    const float* a0r = rows + rp*128;
    const float* a1r = a0r + 128;
    const float4* W4 = (const float4*)W;   // [128][64] f4
    float4* wch4 = (float4*)wch;           // [64][64] f4 per chunk
    float4 acc0 = make_float4(0.f,0.f,0.f,0.f);
    float4 acc1 = make_float4(0.f,0.f,0.f,0.f);
    for (int c = 0; c < 2; ++c) {
        __syncthreads();
        #pragma unroll
        for (int i = 0; i < 16; ++i)
            wch4[t + 256*i] = W4[c*4096 + t + 256*i];
        __syncthreads();
        int kb = c*64;
        #pragma unroll 4
        for (int k = 0; k < 64; k += 4) {
            float4 a0 = *(const float4*)(a0r + kb + k);
            float4 a1 = *(const float4*)(a1r + kb + k);
            float4 w;
            w = wch4[(k+0)*64+cb];
            acc0.x += a0.x*w.x; acc0.y += a0.x*w.y; acc0.z += a0.x*w.z; acc0.w += a0.x*w.w;
            acc1.x += a1.x*w.x; acc1.y += a1.x*w.y; acc1.z += a1.x*w.z; acc1.w += a1.x*w.w;
            w = wch4[(k+1)*64+cb];
            acc0.x += a0.y*w.x; acc0.y += a0.y*w.y; acc0.z += a0.y*w.z; acc0.w += a0.y*w.w;
            acc1.x += a1.y*w.x; acc1.y += a1.y*w.y; acc1.z += a1.y*w.z; acc1.w += a1.y*w.w;
            w = wch4[(k+2)*64+cb];
            acc0.x += a0.z*w.x; acc0.y += a0.z*w.y; acc0.z += a0.z*w.z; acc0.w += a0.z*w.w;
            acc1.x += a1.z*w.x; acc1.y += a1.z*w.y; acc1.z += a1.z*w.z; acc1.w += a1.z*w.w;
            w = wch4[(k+3)*64+cb];
            acc0.x += a0.w*w.x; acc0.y += a0.w*w.y; acc0.z += a0.w*w.z; acc0.w += a0.w*w.w;
            acc1.x += a1.w*w.x; acc1.y += a1.w*w.y; acc1.z += a1.w*w.z; acc1.w += a1.w*w.w;
        }
    }
    float4 b4 = ((const float4*)bi)[cb];
    acc0.x += b4.x; acc0.y += b4.y; acc0.z += b4.z; acc0.w += b4.w;
    acc1.x += b4.x; acc1.y += b4.y; acc1.z += b4.z; acc1.w += b4.w;
    ((float4*)out)[(r0+rp  )*64 + cb] = acc0;
    ((float4*)out)[(r0+rp+1)*64 + cb] = acc1;
}

// ---------------------------------------------------------------------------
// K1: wave-sync knn (0..511) + gemmA (512..1279) + zero stp (1280..1471) +
// dirs norm (1472). knn algorithm verified r8-r12.
// ---------------------------------------------------------------------------
__global__ void k1_kernel(const float* __restrict__ verts, const float* __restrict__ dirs,
                          const float* __restrict__ x,
                          const float* __restrict__ convW, const float* __restrict__ convB,
                          int* __restrict__ idxout, float* __restrict__ sdn,
                          float* __restrict__ stp, float* __restrict__ fo)
{
    __shared__ __align__(16) char smem[21504];
    int t = threadIdx.x;
    int blk = blockIdx.x;

    if (blk >= 1280) {
        if (blk == 1472) {
            for (int i = t; i < 768; i += 256) {
                int l = i >> 7, k = i & 127;
                float a = dirs[l*384 + k];
                float b = dirs[l*384 + 128 + k];
                float c = dirs[l*384 + 256 + k];
                float nrm = sqrtf(a*a + b*b + c*c);
                float inv = 1.0f / fmaxf(nrm, 1e-12f);
                sdn[l*384 + k]       = a*inv;
                sdn[l*384 + 128 + k] = b*inv;
                sdn[l*384 + 256 + k] = c*inv;
            }
        } else {
            stp[(blk - 1280)*256 + t] = 0.0f;     // 192 blocks x 256 = 49152
        }
        return;
    }
    if (blk >= 512) {
        int g = blk - 512;
        int s = g >> 8, rb = g & 255;
        int wi = (s==0) ? 0 : (s==1) ? 1 : 3;
        do_gemm(x, (const float*)0, (const float*)0, (const float*)0,
                convW + wi*32768, convB + wi*256, fo + s*524288, rb, smem);
        return;
    }

    // ---------------- knn: one wave per vertex ----------------
    float* xs  = (float*)smem;
    float* ys  = xs + 1024;
    float* zs  = ys + 1024;
    float* sqs = zs + 1024;
    unsigned int* histBase = (unsigned int*)(smem + 16384);
    unsigned int* selBase  = (unsigned int*)(smem + 20480);

    int w = t >> 6, l = t & 63;
    int vglob = blk*4 + w;
    int b = vglob >> 10;
    int v = vglob & 1023;
    unsigned long long* keys = (unsigned long long*)smem + w*256;  // alias xs/ys
    unsigned int* hist = histBase + w*256;
    unsigned int* sel  = selBase + w*4;

    const float* vb = verts + b * 3072;
    for (int i = t; i < 1024; i += 256) {
        float xx = vb[i*3+0], yy = vb[i*3+1], zz = vb[i*3+2];
        xs[i] = xx; ys[i] = yy; zs[i] = zz;
        sqs[i] = xx*xx + yy*yy + zz*zz;
    }
    __syncthreads();

    float cx = xs[v], cy = ys[v], cz = zs[v], csq = sqs[v];
    unsigned long long K16[16];
    #pragma unroll
    for (int q = 0; q < 16; ++q) {
        int j = q*64 + l;
        float dot = cx*xs[j] + cy*ys[j] + cz*zs[j];
        float d = -2.0f*dot + csq + sqs[j];
        unsigned int u = __float_as_uint(d);
        u = (u & 0x80000000u) ? ~u : (u | 0x80000000u);
        K16[q] = (((unsigned long long)u) << 32) | (unsigned long long)j;
    }
    #pragma unroll
    for (int i = 0; i < 4; ++i) hist[l*4 + i] = 0u;
    __syncthreads();

    #pragma unroll
    for (int q = 0; q < 16; ++q)
        atomicAdd(&hist[(unsigned int)(K16[q] >> 56)], 1u);
    __syncthreads();

    {
        unsigned int h0 = hist[l*4], h1 = hist[l*4+1], h2 = hist[l*4+2], h3 = hist[l*4+3];
        unsigned int c1 = h0, c2 = h0+h1, c3 = h0+h1+h2, T = c3+h3;
        unsigned int xacc = T;
        #pragma unroll
        for (int off = 1; off < 64; off <<= 1) {
            unsigned int y = __shfl_up(xacc, off, 64);
            if (l >= off) xacc += y;
        }
        unsigned int P = xacc - T;
        unsigned int ex[4] = {P, P+c1, P+c2, P+c3};
        unsigned int hh[4] = {h0, h1, h2, h3};
        #pragma unroll
        for (int i = 0; i < 4; ++i) {
            if (ex[i] < 101u && ex[i] + hh[i] >= 101u) {
                sel[0] = (unsigned int)(l*4 + i);
                sel[1] = 101u - ex[i];
            }
        }
    }
    __syncthreads();
    unsigned int P8 = sel[0], rank2 = sel[1];
    #pragma unroll
    for (int i = 0; i < 4; ++i) hist[l*4 + i] = 0u;
    __syncthreads();

    #pragma unroll
    for (int q = 0; q < 16; ++q)
        if ((unsigned int)(K16[q] >> 56) == P8)
            atomicAdd(&hist[(unsigned int)(K16[q] >> 48) & 0xFFu], 1u);
    __syncthreads();

    {
        unsigned int h0 = hist[l*4], h1 = hist[l*4+1], h2 = hist[l*4+2], h3 = hist[l*4+3];
        unsigned int c1 = h0, c2 = h0+h1, c3 = h0+h1+h2, T = c3+h3;
        unsigned int xacc = T;
        #pragma unroll
        for (int off = 1; off < 64; off <<= 1) {
            unsigned int y = __shfl_up(xacc, off, 64);
            if (l >= off) xacc += y;
        }
        unsigned int P = xacc - T;
        unsigned int ex[4] = {P, P+c1, P+c2, P+c3};
        unsigned int hh[4] = {h0, h1, h2, h3};
        #pragma unroll
        for (int i = 0; i < 4; ++i) {
            if (ex[i] < rank2 && ex[i] + hh[i] >= rank2) {
                sel[2] = (P8 << 8) | (unsigned int)(l*4 + i);
                sel[3] = 0u;
            }
        }
    }
    __syncthreads();
    unsigned int P16 = sel[2];

    #pragma unroll
    for (int q = 0; q < 16; ++q) {
        if ((unsigned int)(K16[q] >> 48) <= P16) {
            unsigned int pos = atomicAdd(&sel[3], 1u);
            if (pos < 256u) keys[pos] = K16[q];
        }
    }
    __syncthreads();
    unsigned int cnt = sel[3];

    unsigned long long K[4];
    #pragma unroll
    for (int q = 0; q < 4; ++q) {
        unsigned int e = (unsigned int)(l*4 + q);
        K[q] = (e < cnt) ? keys[e] : 0xFFFFFFFFFFFFFFFFULL;
    }

    auto cswap = [&](int qa, int qb, int k) {
        int e = (l << 2) + qa;
        bool up = ((e & k) == 0);
        unsigned long long a = K[qa], bb2 = K[qb];
        unsigned long long mn = a < bb2 ? a : bb2;
        unsigned long long mx = a < bb2 ? bb2 : a;
        K[qa] = up ? mn : mx;
        K[qb] = up ? mx : mn;
    };
    #pragma unroll
    for (int k = 2; k <= 256; k <<= 1) {
        for (int j = k >> 1; j >= 4; j >>= 1) {
            int lj = j >> 2;
            #pragma unroll
            for (int q = 0; q < 4; ++q) {
                unsigned long long other = __shfl_xor(K[q], lj, 64);
                int e = (l << 2) + q;
                bool up = ((e & k) == 0);
                bool lower = ((l & lj) == 0);
                bool takeMin = (lower == up);
                unsigned long long mn = K[q] < other ? K[q] : other;
                unsigned long long mx = K[q] < other ? other : K[q];
                K[q] = takeMin ? mn : mx;
            }
        }
        if (k >= 4) { cswap(0, 2, k); cswap(1, 3, k); }
        cswap(0, 1, k); cswap(2, 3, k);
    }

    #pragma unroll
    for (int q = 0; q < 4; ++q) {
        int e = l*4 + q;
        if (e >= 1 && e <= 100)
            idxout[vglob*100 + (e-1)] = (int)(K[q] & 0xFFFFFFFFu);
    }
}

// ---------------------------------------------------------------------------
// Agg + fused BN-partials: 256 threads = 2 rows/block. After writing the
// row, each thread adds (val, val^2) into stp bank (row & 31) (64 adds per
// address across the launch; fire-and-forget atomics).
// ---------------------------------------------------------------------------
__global__ void agg_kernel(const int* __restrict__ idx, const float* __restrict__ verts,
                           const float* __restrict__ sdn, const float* __restrict__ fo,
                           int n0, int n1, int n2, int d0, int d1, int d2,
                           float* o0, float* o1, float* o2,
                           float* s0p, float* s1p, float* s2p)
{
    __shared__ float4 ds4s[200];
    __shared__ int jss[200];
    int slot = blockIdx.y;
    int n  = slot==0 ? n0 : slot==1 ? n1 : n2;
    int dI = slot==0 ? d0 : slot==1 ? d1 : d2;
    float* outp = slot==0 ? o0 : slot==1 ? o1 : o2;
    float* stp  = slot==0 ? s0p : slot==1 ? s1p : s2p;
    const float* fos = fo + slot * 524288;
    const float* sd = sdn + dI * 384;

    int t = threadIdx.x;
    int h = t >> 7, tt = t & 127;
    float4* ds4 = ds4s + h*100;
    int* js = jss + h*100;
    int r = blockIdx.x*2 + h;
    int b = r >> 10;

    if (tt < n) {
        int j = idx[r*100 + tt];
        js[tt] = j;
        const float* pj = verts + (b*1024 + j)*3;
        const float* pv = verts + r*3;
        float dx = pj[0]-pv[0], dy = pj[1]-pv[1], dz = pj[2]-pv[2];
        float nm = sqrtf(dx*dx + dy*dy + dz*dz);
        float inv = 1.0f / fmaxf(nm, 1e-12f);
        ds4[tt] = make_float4(dx*inv, dy*inv, dz*inv, 0.0f);
    }
    __syncthreads();
    float s0 = sd[tt], s1 = sd[128+tt], s2 = sd[256+tt];
    int bb = b * 1024;
    float m = -3.0e38f;
    for (int q = 0; q < n; q += 5) {
        float th[5];
        const float* p[5];
        #pragma unroll
        for (int u = 0; u < 5; ++u) {
            float4 dq = ds4[q+u];
            th[u] = fmaxf(dq.x*s0 + dq.y*s1 + dq.z*s2, 0.0f);
            p[u] = fos + (size_t)(bb + js[q+u])*256 + 128 + tt;
        }
        float vv[5];
        #pragma unroll
        for (int u = 0; u < 5; ++u) vv[u] = *p[u];
        #pragma unroll
        for (int u = 0; u < 5; ++u) m = fmaxf(m, th[u]*vv[u]);
    }
    float val = fos[r*256 + tt] + m;
    outp[r*128 + tt] = val;
    float* bank = stp + (r & 31)*256;
    atomicAdd(&bank[tt], val);
    atomicAdd(&bank[128+tt], val*val);
}

// ---------------------------------------------------------------------------
// Standalone gemm (big-chunk body), up to 2 slots via blockIdx.y.
// grid (256, nslots), 256 thr. LDS 69KB -> 2 blocks/CU for K3.
// ---------------------------------------------------------------------------
__global__ void gemm2_kernel(
    const float* inA, const float* stA, const float* gA, const float* beA,
    const float* WA, const float* biA, float* foA,
    const float* inB, const float* stB, const float* gB, const float* beB,
    const float* WB, const float* biB, float* foB)
{
    __shared__ __align__(16) char smem[70656];
    if (blockIdx.y == 0)
        do_gemm_big(inA, stA, gA, beA, WA, biA, foA, blockIdx.x, smem);
    else
        do_gemm_big(inB, stB, gB, beB, WB, biB, foB, blockIdx.x, smem);
}

// ---------------------------------------------------------------------------
// Down-proj: [bn(p0)|bn(p1)|bn(p2)] (384) @ dW + db, relu.
// NEW geometry: 16 rows x 128 cols per block, grid (128,2) = 256 blocks.
// W slice per block = 384x128 (197KB) in 3 chunks of k=128 (64KB each) ->
// 3 exposed chunk boundaries instead of 24. LDS = 91KB/block.
// Thread map: cb = t&31 (col4 within 128-col slice), rg = t>>5 -> rows
// rg*2, rg*2+1 (acc0/acc1).
// ---------------------------------------------------------------------------
__global__ void down_kernel(
    const float* __restrict__ p0, const float* __restrict__ s0p,
    const float* __restrict__ g0, const float* __restrict__ be0,
    const float* __restrict__ p1, const float* __restrict__ s1p,
    const float* __restrict__ g1, const float* __restrict__ be1,
    const float* __restrict__ p2, const float* __restrict__ s2p,
    const float* __restrict__ g2, const float* __restrict__ be2,
    const float* __restrict__ dW, const float* __restrict__ db,
    float* __restrict__ out)
{
    __shared__ __align__(16) float rows[16*384];      // 24 KB
    __shared__ __align__(16) float4 wch4[4096];       // 64 KB  [k=128][cb=32]
    __shared__ float scale[384], shift[384];
    int t = threadIdx.x;
    int r0 = blockIdx.x * 16;
    int colblk = blockIdx.y;                          // 0 or 1

    for (int c = t; c < 384; c += 256) {
        int seg = c >> 7, cc = c & 127;
        const float* stp = seg==0 ? s0p : seg==1 ? s1p : s2p;
        const float* g   = seg==0 ? g0  : seg==1 ? g1  : g2;
        const float* be  = seg==0 ? be0 : seg==1 ? be1 : be2;
        float sm = 0.0f, sq = 0.0f;
        #pragma unroll 8
        for (int bk = 0; bk < 32; ++bk) {
            sm += stp[bk*256 + cc];
            sq += stp[bk*256 + 128 + cc];
        }
        float mu  = sm * (1.0f/2048.0f);
        float var = sq * (1.0f/2048.0f) - mu*mu;
        float s = rsqrtf(var + 1e-5f) * g[cc];
        scale[c] = s;
        shift[c] = be[cc] - mu*s;
    }
    __syncthreads();
    // stage 16 rows x 384 (bn-relu applied): 1536 float4, 6 per thread
    for (int q = t; q < 1536; q += 256) {
        int row = q / 96, rem = q - row*96;
        int c4 = rem << 2;
        int seg = c4 >> 7, cc = c4 & 127;
        const float* ps = seg==0 ? p0 : seg==1 ? p1 : p2;
        float4 v = *(const float4*)(ps + (r0+row)*128 + cc);
        v.x = fmaxf(v.x*scale[c4  ] + shift[c4  ], 0.0f);
        v.y = fmaxf(v.y*scale[c4+1] + shift[c4+1], 0.0f);
        v.z = fmaxf(v.z*scale[c4+2] + shift[c4+2], 0.0f);
        v.w = fmaxf(v.w*scale[c4+3] + shift[c4+3], 0.0f);
        *(float4*)&rows[row*384 + c4] = v;
    }

    int cb = t & 31;
    int rg = t >> 5;
    const float* a0r = rows + (rg*2)*384;
    const float* a1r = a0r + 384;
    const float4* W4 = (const float4*)dW;             // [384][64] f4
    float4 acc0 = make_float4(0.f,0.f,0.f,0.f);
    float4 acc1 = make_float4(0.f,0.f,0.f,0.f);
    for (int c = 0; c < 3; ++c) {
        __syncthreads();   // rows staged (c=0) / chunk c-1 fully consumed
        #pragma unroll
        for (int i = 0; i < 16; ++i) {
            int e = t + 256*i;                        // 0..4095
            wch4[e] = W4[c*8192 + colblk*32 + (e >> 5)*64 + (e & 31)];
        }
        __syncthreads();
        int kb = c*128;
        #pragma unroll 8
        for (int k = 0; k < 128; k += 4) {
            float4 a0 = *(const float4*)(a0r + kb + k);
            float4 a1 = *(const float4*)(a1r + kb + k);
            float4 w;
            w = wch4[(k+0)*32+cb];
            acc0.x += a0.x*w.x; acc0.y += a0.x*w.y; acc0.z += a0.x*w.z; acc0.w += a0.x*w.w;
            acc1.x += a1.x*w.x; acc1.y += a1.x*w.y; acc1.z += a1.x*w.z; acc1.w += a1.x*w.w;
            w = wch4[(k+1)*32+cb];
            acc0.x += a0.y*w.x; acc0.y += a0.y*w.y; acc0.z += a0.y*w.z; acc0.w += a0.y*w.w;
            acc1.x += a1.y*w.x; acc1.y += a1.y*w.y; acc1.z += a1.y*w.z; acc1.w += a1.y*w.w;
            w = wch4[(k+2)*32+cb];
            acc0.x += a0.z*w.x; acc0.y += a0.z*w.y; acc0.z += a0.z*w.z; acc0.w += a0.z*w.w;
            acc1.x += a1.z*w.x; acc1.y += a1.z*w.y; acc1.z += a1.z*w.z; acc1.w += a1.z*w.w;
            w = wch4[(k+3)*32+cb];
            acc0.x += a0.w*w.x; acc0.y += a0.w*w.y; acc0.z += a0.w*w.z; acc0.w += a0.w*w.w;
            acc1.x += a1.w*w.x; acc1.y += a1.w*w.y; acc1.z += a1.w*w.z; acc1.w += a1.w*w.w;
        }
    }
    float4 b4 = ((const float4*)db)[colblk*32 + cb];
    float4 o0, o1;
    o0.x = fmaxf(acc0.x + b4.x, 0.0f); o0.y = fmaxf(acc0.y + b4.y, 0.0f);
    o0.z = fmaxf(acc0.z + b4.z, 0.0f); o0.w = fmaxf(acc0.w + b4.w, 0.0f);
    o1.x = fmaxf(acc1.x + b4.x, 0.0f); o1.y = fmaxf(acc1.y + b4.y, 0.0f);
    o1.z = fmaxf(acc1.z + b4.z, 0.0f); o1.w = fmaxf(acc1.w + b4.w, 0.0f);
    ((float4*)out)[(r0 + rg*2    )*64 + colblk*32 + cb] = o0;
    ((float4*)out)[(r0 + rg*2 + 1)*64 + colblk*32 + cb] = o1;
}

// ---------------------------------------------------------------------------
extern "C" void kernel_launch(void* const* d_in, const int* in_sizes, int n_in,
                              void* d_out, int out_size, void* d_ws, size_t ws_size,
                              hipStream_t stream)
{
    (void)in_sizes; (void)n_in; (void)out_size; (void)ws_size;
    const float* verts = (const float*)d_in[0];
    const float* x     = (const float*)d_in[1];
    const float* convW = (const float*)d_in[2];
    const float* convB = (const float*)d_in[3];
    const float* dirs  = (const float*)d_in[4];
    const float* gam   = (const float*)d_in[5];
    const float* bet   = (const float*)d_in[6];
    const float* dW    = (const float*)d_in[7];
    const float* db    = (const float*)d_in[8];
    float* out = (float*)d_out;

    char* ws = (char*)d_ws;
    int*   idxb = (int*)(ws);
    float* sdn  = (float*)(ws + 819200);
    float* stp  = (float*)(ws + 828416);         // 6 x 32 x 256 f32
    float* fo   = (float*)(ws + 1025024);        // 3 x (2048,256)
    float* p0   = (float*)(ws + 7316480);
    float* p1   = (float*)(ws + 8365056);
    float* p2   = (float*)(ws + 9413632);
    float* p3   = (float*)(ws + 10462208);
    float* p4   = (float*)(ws + 11510784);
    float* p5   = (float*)(ws + 12559360);       // end ~13.0 MiB

    const float* nf = (const float*)0;
    float* nw = (float*)0;
    float* stL0 = stp,         *stL1 = stp + 8192, *stL2 = stp + 16384;
    float* stL3 = stp + 24576, *stL4 = stp + 32768, *stL5 = stp + 40960;

    // K1: knn + gemmA (L0,L1,L3 from x) + zero stp + dirs norm
    k1_kernel<<<1473, 256, 0, stream>>>(verts, dirs, x, convW, convB,
                                        idxb, sdn, stp, fo);
    // K2: aggA -> p0 (n5,d0,stL0), p1 (n20,d1,stL1), p3 (n100,d3,stL3)
    agg_kernel<<<dim3(1024,3), 256, 0, stream>>>(
        idxb, verts, sdn, fo, 5, 20, 100, 0, 1, 3,
        p0, p1, p3, stL0, stL1, stL3);
    // K3: gemmB: L2 from bn(p1,stL1,g1,b1); L4 from bn(p3,stL3,g3,b3)
    gemm2_kernel<<<dim3(256,2), 256, 0, stream>>>(
        p1, stL1, gam + 128, bet + 128, convW + 65536,  convB + 512,  fo,
        p3, stL3, gam + 384, bet + 384, convW + 131072, convB + 1024, fo + 524288);
    // K4: aggB -> p2 (n20,d2,stL2), p4 (n100,d4,stL4)
    agg_kernel<<<dim3(1024,2), 256, 0, stream>>>(
        idxb, verts, sdn, fo, 20, 100, 0, 2, 4, 0,
        p2, p4, nw, stL2, stL4, nw);
    // K5: gemmC: L5-conv (params3) from bn(p4,stL4,g4,b4)
    gemm2_kernel<<<dim3(256,1), 256, 0, stream>>>(
        p4, stL4, gam + 512, bet + 512, convW + 98304, convB + 768, fo,
        nf, nf, nf, nf, nf, nf, nw);
    // K6: aggC -> p5 (n100,d3,stL5)
    agg_kernel<<<dim3(1024,1), 256, 0, stream>>>(
        idxb, verts, sdn, fo, 100, 0, 0, 3, 0, 0,
        p5, nw, nw, stL5, nw, nw);
    // K7: down: bn(p0,stL0,g0,b0) | bn(p2,stL2,g2,b2) | bn(p5,stL5,g3,b3)
    down_kernel<<<dim3(128,2), 256, 0, stream>>>(
        p0, stL0, gam, bet,
        p2, stL2, gam + 256, bet + 256,
        p5, stL5, gam + 384, bet + 384,
        dW, db, out);
}